// Round 2
// baseline (245.148 us; speedup 1.0000x reference)
//
#include <hip/hip_runtime.h>
#include <math.h>

// DotProductAttention: B=1, H=16, S=4096, D=64, fp32 in/out, no scale, softmax(QK^T)V.
// Flash-attention forward with fp16 MFMA (16x16x32), fp32 accumulation.
// fp16 (not bf16): same MFMA rate on gfx950, 8x less rounding error -> passes
// the 9.4e-2 absmax threshold with margin.
// Block = 256 threads (4 waves). Each block: one head, 64 q-rows (16 per wave).
// KV tiles of 64 rows staged in LDS (K row-major, V transposed), padded stride 68
// (34 dwords) -> all LDS accesses at per-instruction bank minimum.

#define HH 16
#define SS 4096
#define DD 64
#define QB 64
#define KB 64
#define NTILES (SS / KB)
#define LDP 68  // padded LDS row stride in halfs (136 B = 34 dwords)

typedef __attribute__((ext_vector_type(4))) _Float16 half4_t;
typedef __attribute__((ext_vector_type(8))) _Float16 half8_t;
typedef __attribute__((ext_vector_type(4))) float f32x4;

__device__ inline half8_t ld_frag(const _Float16* p) {
  half4_t lo = *(const half4_t*)p;
  half4_t hi = *(const half4_t*)(p + 4);
  return __builtin_shufflevector(lo, hi, 0, 1, 2, 3, 4, 5, 6, 7);
}

__global__ __launch_bounds__(256, 2)
void attn_fwd(const float* __restrict__ Q, const float* __restrict__ K,
              const float* __restrict__ V, float* __restrict__ O) {
  __shared__ _Float16 K_lds[KB][LDP];    // [kv][d]
  __shared__ _Float16 V_lds[DD][LDP];    // transposed: [d][kv]
  __shared__ _Float16 P_lds[4][16][LDP]; // per-wave [q][kv]

  const int tid  = threadIdx.x;
  const int wave = tid >> 6;
  const int lane = tid & 63;
  const int g    = lane >> 4;   // 16-lane group 0..3
  const int m16  = lane & 15;

  const int head  = blockIdx.y;
  const int qtile = blockIdx.x;
  const int qw    = qtile * QB + wave * 16;  // this wave's q-row base

  const size_t headoff = (size_t)head * SS * DD;

  // ---- Q fragments: A-frag layout, lane holds Q[qw + m16][8g + 32ks + e] ----
  half8_t qf[2];
  {
    const float* qrow = Q + headoff + (size_t)(qw + m16) * DD + 8 * g;
    for (int ks = 0; ks < 2; ++ks) {
      float4 a = *(const float4*)(qrow + 32 * ks);
      float4 b = *(const float4*)(qrow + 32 * ks + 4);
      half8_t f;
      f[0] = (_Float16)a.x; f[1] = (_Float16)a.y; f[2] = (_Float16)a.z; f[3] = (_Float16)a.w;
      f[4] = (_Float16)b.x; f[5] = (_Float16)b.y; f[6] = (_Float16)b.z; f[7] = (_Float16)b.w;
      qf[ks] = f;
    }
  }

  f32x4 acc_o[4] = {};            // [dtile]: O[q=4g+r][d=16dt+m16]
  float m_run[4], l_run[4];
#pragma unroll
  for (int r = 0; r < 4; ++r) { m_run[r] = -INFINITY; l_run[r] = 0.f; }

  for (int t = 0; t < NTILES; ++t) {
    const int kv0 = t * KB;
    __syncthreads();  // previous iteration's readers done before restaging

    // ---- stage K tile (row-major, fp32 -> fp16) ----
    {
      const int c4 = (tid & 15) * 4;
#pragma unroll
      for (int it = 0; it < 4; ++it) {
        const int row = (tid >> 4) + 16 * it;
        float4 kx = *(const float4*)(K + headoff + (size_t)(kv0 + row) * DD + c4);
        half4_t w;
        w[0] = (_Float16)kx.x; w[1] = (_Float16)kx.y;
        w[2] = (_Float16)kx.z; w[3] = (_Float16)kx.w;
        *(half4_t*)&K_lds[row][c4] = w;
      }
    }
    // ---- stage V tile transposed: V_lds[d][kv] ----
    {
      const int d = lane;
#pragma unroll
      for (int it = 0; it < 4; ++it) {
        const int kvb = 4 * wave + 16 * it;
        const float* vp = V + headoff + (size_t)(kv0 + kvb) * DD + d;
        half4_t w;
        w[0] = (_Float16)vp[0];
        w[1] = (_Float16)vp[DD];
        w[2] = (_Float16)vp[2 * DD];
        w[3] = (_Float16)vp[3 * DD];
        *(half4_t*)&V_lds[d][kvb] = w;
      }
    }
    __syncthreads();

    // ---- S = Q K^T  (per wave: 16 x 64) ----
    f32x4 s[4] = {};
#pragma unroll
    for (int ks = 0; ks < 2; ++ks) {
      const int d0 = 8 * g + 32 * ks;
#pragma unroll
      for (int nt = 0; nt < 4; ++nt) {
        half8_t kb = ld_frag(&K_lds[nt * 16 + m16][d0]);
        s[nt] = __builtin_amdgcn_mfma_f32_16x16x32_f16(qf[ks], kb, s[nt], 0, 0, 0);
      }
    }

    // ---- online softmax (rows q = 4g + r; reduce over kv = lanes m16) ----
    float corr[4];
#pragma unroll
    for (int r = 0; r < 4; ++r) {
      float mx = fmaxf(fmaxf(s[0][r], s[1][r]), fmaxf(s[2][r], s[3][r]));
#pragma unroll
      for (int off = 1; off <= 8; off <<= 1) mx = fmaxf(mx, __shfl_xor(mx, off, 64));
      const float mnew = fmaxf(m_run[r], mx);
      const float c = __expf(m_run[r] - mnew);
      corr[r] = c;
      m_run[r] = mnew;
      float sum = 0.f;
#pragma unroll
      for (int nt = 0; nt < 4; ++nt) {
        float p = __expf(s[nt][r] - mnew);
        s[nt][r] = p;
        sum += p;
      }
#pragma unroll
      for (int off = 1; off <= 8; off <<= 1) sum += __shfl_xor(sum, off, 64);
      l_run[r] = l_run[r] * c + sum;
    }
#pragma unroll
    for (int dt = 0; dt < 4; ++dt)
#pragma unroll
      for (int r = 0; r < 4; ++r) acc_o[dt][r] *= corr[r];

    // ---- P -> LDS (fp16), then PV via MFMA ----
#pragma unroll
    for (int nt = 0; nt < 4; ++nt)
#pragma unroll
      for (int r = 0; r < 4; ++r)
        P_lds[wave][4 * g + r][nt * 16 + m16] = (_Float16)s[nt][r];

#pragma unroll
    for (int ks = 0; ks < 2; ++ks) {
      const int k0 = 8 * g + 32 * ks;
      half8_t pa = ld_frag(&P_lds[wave][m16][k0]);
#pragma unroll
      for (int dt = 0; dt < 4; ++dt) {
        half8_t vb = ld_frag(&V_lds[dt * 16 + m16][k0]);
        acc_o[dt] = __builtin_amdgcn_mfma_f32_16x16x32_f16(pa, vb, acc_o[dt], 0, 0, 0);
      }
    }
  }

  // ---- epilogue: normalize and store ----
#pragma unroll
  for (int r = 0; r < 4; ++r) {
    const float inv = 1.f / l_run[r];
    float* orow = O + headoff + (size_t)(qw + 4 * g + r) * DD + m16;
#pragma unroll
    for (int dt = 0; dt < 4; ++dt) orow[16 * dt] = acc_o[dt][r] * inv;
  }
}

extern "C" void kernel_launch(void* const* d_in, const int* in_sizes, int n_in,
                              void* d_out, int out_size, void* d_ws, size_t ws_size,
                              hipStream_t stream) {
  const float* Q = (const float*)d_in[0];
  const float* K = (const float*)d_in[1];
  const float* V = (const float*)d_in[2];
  float* O = (float*)d_out;
  dim3 grid(SS / QB, HH, 1);
  attn_fwd<<<grid, dim3(256, 1, 1), 0, stream>>>(Q, K, V, O);
}

// Round 3
// 111.166 us; speedup vs baseline: 2.2052x; 2.2052x over previous
//
#include <hip/hip_runtime.h>
#include <math.h>

// DotProductAttention: B=1,H=16,S=4096,D=64, fp32 in/out, no scale.
// 8-wave flash-attn, mfma_f32_32x32x16_f16, swapped QK^T -> in-register softmax.
// Each wave owns 32 q-rows; block = 256 q-rows; grid = 16 qtiles x 16 heads = 256 blocks.
// K row-major + V transposed staged in LDS (stride 144B = odd*16 -> conflict-free b128).
// Double-buffered LDS, reg-staged async global loads, defer-max rescale (THR=8).

#define HH 16
#define SS 4096
#define DDm 64
#define WAVES 8
#define QBW 32
#define QB (WAVES * QBW)
#define KB 64
#define NTL (SS / KB)
#define LDP 72  // f16 stride = 144 B = 9*16 B

typedef __attribute__((ext_vector_type(2))) _Float16 half2_t;
typedef __attribute__((ext_vector_type(8))) _Float16 half8_t;
typedef __attribute__((ext_vector_type(16))) float f32x16;

union H8 { half2_t h2[4]; half8_t v; };
union FU { float f; unsigned u; };
union HU { half2_t h; unsigned u; };

__device__ inline unsigned asu(float x){ FU c; c.f=x; return c.u; }
__device__ inline float    asf(unsigned x){ FU c; c.u=x; return c.f; }
__device__ inline unsigned h2u(half2_t x){ HU c; c.h=x; return c.u; }
__device__ inline half2_t  u2h(unsigned x){ HU c; c.u=x; return c.h; }
__device__ inline half2_t  pk2(float a, float b){ half2_t h; h[0]=(_Float16)a; h[1]=(_Float16)b; return h; }

#if __has_builtin(__builtin_amdgcn_permlane32_swap)
#define HAVE_PL32 1
typedef __attribute__((ext_vector_type(2))) unsigned uint2_t;
__device__ inline uint2_t pl32(unsigned a, unsigned b){
  return __builtin_amdgcn_permlane32_swap(a, b, false, false);
}
#else
#define HAVE_PL32 0
#endif

__global__ __launch_bounds__(512, 2)
void attn_fwd(const float* __restrict__ Q, const float* __restrict__ K,
              const float* __restrict__ V, float* __restrict__ O) {
  __shared__ __align__(16) _Float16 Klds[2][KB][LDP];  // [buf][kv][d]
  __shared__ __align__(16) _Float16 Vt  [2][DDm][LDP]; // [buf][d][kv]

  const int tid  = threadIdx.x;
  const int lane = tid & 63;
  const int lo5  = lane & 31;
  const int hi   = lane >> 5;

  const int lid  = blockIdx.x;
  const int head = 2 * (lid & 7) + ((lid >> 3) & 1);  // 2 heads per XCD (L2 locality)
  const int qt   = lid >> 4;
  const int qbase = qt * QB + (tid >> 6) * QBW;
  const size_t hoff = (size_t)head * SS * DDm;

  // ---- Q B-frags: lane holds Q[qbase+lo5][16ds+8hi+e], e=0..7 ----
  H8 qf[4];
  {
    const float* qp = Q + hoff + (size_t)(qbase + lo5) * DDm;
#pragma unroll
    for (int ds = 0; ds < 4; ++ds) {
      float4 a = *(const float4*)(qp + 16 * ds + 8 * hi);
      float4 b = *(const float4*)(qp + 16 * ds + 8 * hi + 4);
      qf[ds].h2[0] = pk2(a.x, a.y); qf[ds].h2[1] = pk2(a.z, a.w);
      qf[ds].h2[2] = pk2(b.x, b.y); qf[ds].h2[3] = pk2(b.z, b.w);
    }
  }

  // ---- staging roles ----
  const int krow = tid >> 3, kc8 = (tid & 7) * 8;  // K: 64 rows x 8 col-groups
  const int vd = tid & 63, vk8 = (tid >> 6) * 8;   // V^T: d = lane, 8-kv group per wave

  float4 ka, kb; float va[8];
  auto issue = [&](int t) {
    const float* kp = K + hoff + (size_t)(t * KB + krow) * DDm + kc8;
    ka = *(const float4*)kp;
    kb = *(const float4*)(kp + 4);
    const float* vp = V + hoff + (size_t)(t * KB + vk8) * DDm + vd;
#pragma unroll
    for (int j = 0; j < 8; ++j) va[j] = vp[j * DDm];
  };
  auto wstage = [&](int buf) {
    H8 kw;
    kw.h2[0] = pk2(ka.x, ka.y); kw.h2[1] = pk2(ka.z, ka.w);
    kw.h2[2] = pk2(kb.x, kb.y); kw.h2[3] = pk2(kb.z, kb.w);
    *(half8_t*)&Klds[buf][krow][kc8] = kw.v;
    H8 vw;
#pragma unroll
    for (int j = 0; j < 4; ++j) vw.h2[j] = pk2(va[2 * j], va[2 * j + 1]);
    *(half8_t*)&Vt[buf][vd][vk8] = vw.v;
  };

  f32x16 acc[2];
#pragma unroll
  for (int nt = 0; nt < 2; ++nt)
#pragma unroll
    for (int r = 0; r < 16; ++r) acc[nt][r] = 0.f;
  float m_run = -INFINITY, l_run = 0.f;

  issue(0); wstage(0); __syncthreads();

  for (int t = 0; t < NTL; ++t) {
    const int cur = t & 1;
    if (t + 1 < NTL) issue(t + 1);

#pragma unroll
    for (int s = 0; s < 2; ++s) {
      const int rs = 32 * s;
      // ---- S^T = K * Q^T : lane holds S[q=lo5][kv = rs+(r&3)+8(r>>2)+4hi] ----
      f32x16 st;
#pragma unroll
      for (int r = 0; r < 16; ++r) st[r] = 0.f;
#pragma unroll
      for (int ds = 0; ds < 4; ++ds) {
        half8_t af = *(const half8_t*)&Klds[cur][rs + lo5][16 * ds + 8 * hi];
        st = __builtin_amdgcn_mfma_f32_32x32x16_f16(af, qf[ds].v, st, 0, 0, 0);
      }
      // ---- row max (15 fmax + cross-half combine) ----
      float tmax = st[0];
#pragma unroll
      for (int r = 1; r < 16; ++r) tmax = fmaxf(tmax, st[r]);
#if HAVE_PL32
      { uint2_t pr = pl32(asu(tmax), asu(tmax)); tmax = fmaxf(asf(pr[0]), asf(pr[1])); }
#else
      tmax = fmaxf(tmax, __shfl_xor(tmax, 32, 64));
#endif
      // ---- defer-max rescale (rare) ----
      if (__any(tmax > m_run + 8.f)) {
        float mnew = fmaxf(m_run, tmax);
        float corr = __expf(m_run - mnew);
        m_run = mnew; l_run *= corr;
#pragma unroll
        for (int r = 0; r < 16; ++r) {
          const int qr = (r & 3) + 8 * (r >> 2) + 4 * hi;
          float cf = asf(__builtin_amdgcn_ds_bpermute(qr << 2, asu(corr)));
          acc[0][r] *= cf; acc[1][r] *= cf;
        }
      }
      // ---- exp + row sum ----
      float p[16]; float lsum = 0.f;
#pragma unroll
      for (int r = 0; r < 16; ++r) { p[r] = __expf(st[r] - m_run); lsum += p[r]; }
#if HAVE_PL32
      { uint2_t pr = pl32(asu(lsum), asu(lsum)); lsum = asf(pr[0]) + asf(pr[1]); }
#else
      lsum += __shfl_xor(lsum, 32, 64);
#endif
      l_run += lsum;
      // ---- pack P -> PV A-frags (per 16-kv step) ----
      H8 pa[2];
#pragma unroll
      for (int step = 0; step < 2; ++step) {
        const int b = 8 * step;
        half2_t x0 = pk2(p[b + 0], p[b + 1]);
        half2_t x1 = pk2(p[b + 2], p[b + 3]);
        half2_t y0 = pk2(p[b + 4], p[b + 5]);
        half2_t y1 = pk2(p[b + 6], p[b + 7]);
#if HAVE_PL32
        uint2_t sA = pl32(h2u(x0), h2u(y0));
        uint2_t sB = pl32(h2u(x1), h2u(y1));
        pa[step].h2[0] = u2h(sA[0]); pa[step].h2[1] = u2h(sB[0]);
        pa[step].h2[2] = u2h(sA[1]); pa[step].h2[3] = u2h(sB[1]);
#else
        half2_t sx0 = u2h(__shfl_xor(h2u(x0), 32, 64));
        half2_t sx1 = u2h(__shfl_xor(h2u(x1), 32, 64));
        half2_t sy0 = u2h(__shfl_xor(h2u(y0), 32, 64));
        half2_t sy1 = u2h(__shfl_xor(h2u(y1), 32, 64));
        pa[step].h2[0] = hi ? sy0 : x0;  pa[step].h2[1] = hi ? sy1 : x1;
        pa[step].h2[2] = hi ? y0 : sx0;  pa[step].h2[3] = hi ? y1 : sx1;
#endif
      }
      // ---- PV: acc[nt] += P(32q x 16kv) * V(16kv x 32d) ----
#pragma unroll
      for (int step = 0; step < 2; ++step)
#pragma unroll
        for (int nt = 0; nt < 2; ++nt) {
          half8_t vb = *(const half8_t*)&Vt[cur][32 * nt + lo5][rs + 16 * step + 8 * hi];
          acc[nt] = __builtin_amdgcn_mfma_f32_32x32x16_f16(pa[step].v, vb, acc[nt], 0, 0, 0);
        }
    }

    __syncthreads();
    if (t + 1 < NTL) wstage((t + 1) & 1);
    __syncthreads();
  }

  // ---- epilogue: O[q][d] = acc / l ----
  const float invl = 1.f / l_run;
#pragma unroll
  for (int r = 0; r < 16; ++r) {
    const int qr = (r & 3) + 8 * (r >> 2) + 4 * hi;
    float il = asf(__builtin_amdgcn_ds_bpermute(qr << 2, asu(invl)));
    float* op = O + hoff + (size_t)(qbase + qr) * DDm + lo5;
    op[0]  = acc[0][r] * il;
    op[32] = acc[1][r] * il;
  }
}

extern "C" void kernel_launch(void* const* d_in, const int* in_sizes, int n_in,
                              void* d_out, int out_size, void* d_ws, size_t ws_size,
                              hipStream_t stream) {
  const float* Q = (const float*)d_in[0];
  const float* K = (const float*)d_in[1];
  const float* V = (const float*)d_in[2];
  float* O = (float*)d_out;
  attn_fwd<<<dim3(256, 1, 1), dim3(512, 1, 1), 0, stream>>>(Q, K, V, O);
}